// Round 5
// baseline (115.399 us; speedup 1.0000x reference)
//
#include <hip/hip_runtime.h>
#include <cmath>

// Static problem config (matches reference)
#define RB 20
#define RA 19
#define NPT (RB*RA)
#define DZ 25
#define DIN 9
#define MULT 128
#define CH 128

// ---------------------------------------------------------------------------
// Real-Gaunt selection rules (exact superset of nonzeros; verified R3/R4:
// same absmax as dense). 162 of 2025 (d1,d2,dz) entries survive.
__host__ __device__ constexpr int L_of(int d) { return d == 0 ? 0 : d < 4 ? 1 : d < 9 ? 2 : d < 16 ? 3 : 4; }
__host__ __device__ constexpr int M_of(int d) { return d - L_of(d) * L_of(d) - L_of(d); }
__host__ __device__ constexpr bool gz_nz(int d1, int d2, int dz) {
    const int l1 = L_of(d1), l2 = L_of(d2), l3 = L_of(dz);
    const int m1 = M_of(d1), m2 = M_of(d2), m3 = M_of(dz);
    const int lo = l1 > l2 ? l1 - l2 : l2 - l1;
    if (l3 < lo || l3 > l1 + l2) return false;
    if ((l1 + l2 + l3) & 1) return false;
    const int a1 = m1 < 0 ? -m1 : m1, a2 = m2 < 0 ? -m2 : m2, a3 = m3 < 0 ? -m3 : m3;
    const int sum = a1 + a2, dif = a1 > a2 ? a1 - a2 : a2 - a1;
    if (a3 != sum && a3 != dif) return false;
    if (((m1 < 0) + (m2 < 0) + (m3 < 0)) & 1) return false;
    return true;
}
template<int DZ0, int DZ1>
__host__ __device__ constexpr bool pair_any_r(int d1, int d2) {
    for (int dz = DZ0; dz < DZ1; ++dz) if (gz_nz(d1, d2, dz)) return true;
    return false;
}

// ---------------------------------------------------------------------------
// Host: transposed dense real-Gaunt table Gt[d1*9+d2][28] in fp64 from the
// reference's own quadrature. Cols 25..27 zero pads. Rule-zero entries
// (~1e-16 quadrature noise) forced to exactly 0.0f.
static void host_build_gaunt(float* out /* 81*28, zero-padded */) {
    const double PI = 3.14159265358979323846;
    double xq[RB], wq[RB];
    for (int i = 0; i < RB; ++i) {
        double x = cos(PI * (i + 0.75) / (RB + 0.5));
        double dp = 0.0;
        for (int it = 0; it < 100; ++it) {
            double p0 = 1.0, p1 = x;
            for (int k = 2; k <= RB; ++k) {
                double p2 = ((2.0*k - 1.0)*x*p1 - (k - 1.0)*p0) / (double)k;
                p0 = p1; p1 = p2;
            }
            dp = RB * (x*p1 - p0) / (x*x - 1.0);
            double dx = p1 / dp;
            x -= dx;
            if (fabs(dx) < 1e-15) break;
        }
        {
            double p0 = 1.0, p1 = x;
            for (int k = 2; k <= RB; ++k) {
                double p2 = ((2.0*k - 1.0)*x*p1 - (k - 1.0)*p0) / (double)k;
                p0 = p1; p1 = p2;
            }
            dp = RB * (x*p1 - p0) / (x*x - 1.0);
        }
        xq[i] = x;
        wq[i] = 2.0 / ((1.0 - x*x)*dp*dp);
    }
    static double Y[DZ][NPT];
    static double qws[NPT];
    for (int b = 0; b < RB; ++b) {
        double ct = xq[b], st = sqrt(fmax(0.0, 1.0 - ct*ct));
        double P[5][5]; double pmm = 1.0;
        for (int m = 0; m <= 4; ++m) {
            if (m > 0) pmm *= -(2.0*m - 1.0) * st;
            P[m][m] = pmm;
            if (m < 4) {
                double pp = pmm, pc = ct*(2.0*m + 1.0)*pmm;
                P[m+1][m] = pc;
                for (int l = m + 2; l <= 4; ++l) {
                    double pn = ((2.0*l - 1.0)*ct*pc - (double)(l + m - 1)*pp) / (double)(l - m);
                    P[l][m] = pn; pp = pc; pc = pn;
                }
            }
        }
        for (int a = 0; a < RA; ++a) {
            int pt = b*RA + a;
            qws[pt] = wq[b] * (2.0*PI/(double)RA);
            double alpha = 2.0*PI*(double)a/(double)RA;
            for (int l = 0; l <= 4; ++l)
                for (int m = -l; m <= l; ++m) {
                    int am = m < 0 ? -m : m;
                    double fr = 1.0;
                    for (int i = l - am + 1; i <= l + am; ++i) fr *= (double)i;
                    double nlm = sqrt((2.0*l + 1.0) / (4.0*PI) / fr);
                    double ang = (m == 0) ? 1.0
                               : (m > 0 ? sqrt(2.0)*cos(am*alpha) : sqrt(2.0)*sin(am*alpha));
                    Y[l*l + l + m][pt] = nlm * P[l][am] * ang;
                }
        }
    }
    for (int pr = 0; pr < 81; ++pr) {
        int d1 = pr / 9, d2 = pr % 9;
        for (int d = 0; d < DZ; ++d) {
            double s = 0.0;
            for (int p = 0; p < NPT; ++p)
                s += Y[d][p] * Y[d1][p] * Y[d2][p] * qws[p];
            out[pr*28 + d] = gz_nz(d1, d2, d) ? (float)s : 0.0f;
        }
    }
}

// ---------------------------------------------------------------------------
// Sparse stage C (R4-proven), compile-time unrolled over dz range [DZ0,DZ1).
// Same (d1 asc, d2 asc, dz asc) order among nonzero terms -> bit-identical.
template<int DZ0, int DZ1, int D1, int D2, int DZi>
__device__ __forceinline__ void c_dz(const float* __restrict__ g, float p0, float p1,
                                     float* a0, float* a1) {
    if constexpr (DZi < DZ1) {
        if constexpr (gz_nz(D1, D2, DZi)) {
            const float gv = g[(D1 * 9 + D2) * 28 + DZi];   // b32 broadcast
            a0[DZi - DZ0] = fmaf(p0, gv, a0[DZi - DZ0]);
            a1[DZi - DZ0] = fmaf(p1, gv, a1[DZi - DZ0]);
        }
        c_dz<DZ0, DZ1, D1, D2, DZi + 1>(g, p0, p1, a0, a1);
    }
}
template<int DZ0, int DZ1, int D1, int D2>
__device__ __forceinline__ void c_d2(const float* __restrict__ g,
                                     const float* x0, const float* x1,
                                     const float* y0, const float* y1,
                                     float* a0, float* a1) {
    if constexpr (D2 < 9) {
        if constexpr (pair_any_r<DZ0, DZ1>(D1, D2))
            c_dz<DZ0, DZ1, D1, D2, DZ0>(g, x0[D1] * y0[D2], x1[D1] * y1[D2], a0, a1);
        c_d2<DZ0, DZ1, D1, D2 + 1>(g, x0, x1, y0, y1, a0, a1);
    }
}
template<int DZ0, int DZ1, int D1>
__device__ __forceinline__ void c_d1(const float* __restrict__ g,
                                     const float* x0, const float* x1,
                                     const float* y0, const float* y1,
                                     float* a0, float* a1) {
    if constexpr (D1 < 9) {
        c_d2<DZ0, DZ1, D1, 0>(g, x0, x1, y0, y1, a0, a1);
        c_d1<DZ0, DZ1, D1 + 1>(g, x0, x1, y0, y1, a0, a1);
    }
}

// ---------------------------------------------------------------------------
// Stage D: wave owns l-aligned d-range [D0,D0+ND) (wz block read once per
// wave), lane owns e-PAIR (2*lane, 2*lane+1) -> float2 wz loads (half the
// load instructions of the lane/lane+64 mapping). Ping-pong prefetch: chunk
// i+1's loads issue before chunk i's fma (static reg names, no scratch).
// Per-(e,d) accumulation order (c0 asc, k asc) identical to R4 -> bit-exact.
template<int D0, int ND, int L0, int NL>
__device__ __forceinline__ void d_tile(const float* sZ, const float* __restrict__ wz,
                                       float* __restrict__ po, int lane) {
    const float s128 = 0.08838834764831845f;
    const int e2 = lane << 1;
    float acc[ND * 4];
    #pragma unroll
    for (int i = 0; i < ND * 4; ++i) acc[i] = 0.f;
    float2 wA[NL * 4], wB[NL * 4];

    #define LOADW_D(W, C0) { \
        _Pragma("unroll") \
        for (int j = 0; j < NL; ++j) { \
            _Pragma("unroll") \
            for (int k = 0; k < 4; ++k) \
                W[j * 4 + k] = *(const float2*)(wz + (L0 + j) * 16384 + ((C0) + k) * 128 + e2); \
        } }
    #define FMA_D(W, C0) { \
        _Pragma("unroll") \
        for (int i = 0; i < ND; ++i) { \
            const int d = D0 + i; \
            const int l = (d == 0) ? 0 : (d < 4) ? 1 : (d < 9) ? 2 : (d < 16) ? 3 : 4; \
            float4 z0 = *(const float4*)(sZ + d * 128 + (C0));          /* node0 bcast */ \
            float4 z1 = *(const float4*)(sZ + (25 + d) * 128 + (C0));   /* node1 bcast */ \
            _Pragma("unroll") \
            for (int k = 0; k < 4; ++k) { \
                float zc0 = (k == 0) ? z0.x : (k == 1) ? z0.y : (k == 2) ? z0.z : z0.w; \
                float zc1 = (k == 0) ? z1.x : (k == 1) ? z1.y : (k == 2) ? z1.z : z1.w; \
                acc[i*4+0] = fmaf(zc0, W[(l - L0) * 4 + k].x, acc[i*4+0]); \
                acc[i*4+1] = fmaf(zc0, W[(l - L0) * 4 + k].y, acc[i*4+1]); \
                acc[i*4+2] = fmaf(zc1, W[(l - L0) * 4 + k].x, acc[i*4+2]); \
                acc[i*4+3] = fmaf(zc1, W[(l - L0) * 4 + k].y, acc[i*4+3]); \
            } \
        } }

    LOADW_D(wA, 0);
    for (int c0 = 0; c0 < CH; c0 += 8) {
        LOADW_D(wB, c0 + 4);                      // prefetch next chunk
        FMA_D(wA, c0);
        if (c0 < CH - 8) LOADW_D(wA, c0 + 8);     // prefetch chunk after
        FMA_D(wB, c0 + 4);
    }
    #undef LOADW_D
    #undef FMA_D

    #pragma unroll
    for (int i = 0; i < ND; ++i) {
        po[e2 * 25 + D0 + i]              = acc[i*4+0] * s128;
        po[(e2 + 1) * 25 + D0 + i]        = acc[i*4+1] * s128;
        po[3200 + e2 * 25 + D0 + i]       = acc[i*4+2] * s128;
        po[3200 + (e2 + 1) * 25 + D0 + i] = acc[i*4+3] * s128;
    }
}

// ---------------------------------------------------------------------------
// Fully fused, 2 nodes per block, 256 threads. R4 structure (3 barriers,
// sparse C, direct-global D stores) + R5 latency-hiding:
//  - Stage B remapped to wave=(side,node), lane->c-pair: float2 w loads,
//    HALF the LDS x-broadcast reads (9 vs 18 b128/chunk), b64 sXc writes.
//  - Stage D remapped to e-pair: float2 wz loads (half the instructions).
//  - Explicit ping-pong prefetch of w chunks in B and D.
// All per-output fma orders unchanged -> bit-identical results.
__global__ __launch_bounds__(256) void gaunt_fused(
    const float* __restrict__ xg, const float* __restrict__ yg,
    const float* __restrict__ wxg, const float* __restrict__ wyg,
    const float* __restrict__ wzg, float* __restrict__ outg,
    const float* __restrict__ gGt) {

    // LDS pool (floats), 17884 = 71536 B (2 blocks/CU; grid 512 on 256 CUs
    // caps residency at 2 blocks/CU anyway):
    //  sZ   [0,     6400)  z [n][dz][c]                 (C writes, D reads)
    //  sXY  [6400, 11008)  x,y transposed [side][n][d*128+m]  (A/B)
    //  sXc  [11008,15616)  xc [side][d][n][c]           (B/C)
    //  sG   [15616,17884)  Gaunt table                  (loaded A, read C)
    __shared__ __align__(16) float pool[17884];
    float* sZ  = pool;
    float* sXY = pool + 6400;
    float* sXc = pool + 11008;
    float* sG  = pool + 15616;

    const int tid  = threadIdx.x;
    const int b    = blockIdx.x;
    const int lane = tid & 63;
    const int wave = __builtin_amdgcn_readfirstlane(tid >> 6);
    const float s128 = 0.08838834764831845f;   // 1/sqrt(128)

    // Stage A: x,y for nodes 2b,2b+1 -> transposed sXY; Gaunt table -> sG
    {
        const float4* xs = (const float4*)(xg + 2 * b * 1152);
        const float4* ys = (const float4*)(yg + 2 * b * 1152);
        for (int i = tid; i < 1152; i += 256) {
            float4 v = (i < 576) ? xs[i] : ys[i - 576];
            int r = (i < 576) ? i : i - 576;
            int base = (i < 576) ? 0 : 2304;
            int j0 = r * 4;
            #pragma unroll
            for (int k = 0; k < 4; ++k) {
                int j = j0 + k;
                int n = j / 1152;
                int jj = j - n * 1152;
                int m = jj / 9, d = jj - 9 * m;
                float val = (k == 0) ? v.x : (k == 1) ? v.y : (k == 2) ? v.z : v.w;
                sXY[base + n * 1152 + d * 128 + m] = val;
            }
        }
        for (int i = tid; i < 567; i += 256)
            ((float4*)sG)[i] = ((const float4*)gGt)[i];
    }
    __syncthreads();

    // Stage B: linear_in. wave=(side,node); lane owns c-pair (2*lane,2*lane+1).
    // float2 w loads (coalesced 512B/instr), 9 b128 x-broadcasts per chunk,
    // ping-pong prefetch one chunk ahead. Per-(n,c,d) m-order unchanged.
    {
        const int side = wave >> 1, n = wave & 1;
        const int c2 = lane << 1;
        const float* wb = side ? wyg : wxg;
        const float* xb = sXY + side * 2304 + n * 1152;   // [d*128+m]
        float acc[18];                                     // [d][cpair]
        #pragma unroll
        for (int i = 0; i < 18; ++i) acc[i] = 0.f;
        float2 wA[12], wB[12];                             // [lblk*4+k]

        #define LOADW_B(W, M0) { \
            _Pragma("unroll") \
            for (int k = 0; k < 4; ++k) { \
                W[k]     = *(const float2*)(wb + ((M0) + k) * 128 + c2); \
                W[4 + k] = *(const float2*)(wb + 16384 + ((M0) + k) * 128 + c2); \
                W[8 + k] = *(const float2*)(wb + 32768 + ((M0) + k) * 128 + c2); \
            } }
        #define FMA_B(W, M0) { \
            _Pragma("unroll") \
            for (int d = 0; d < 9; ++d) { \
                const int lb = (d == 0) ? 0 : (d < 4) ? 4 : 8; \
                float4 xv = *(const float4*)(xb + d * 128 + (M0));   /* bcast */ \
                acc[d*2+0] = fmaf(xv.x, W[lb+0].x, acc[d*2+0]); \
                acc[d*2+0] = fmaf(xv.y, W[lb+1].x, acc[d*2+0]); \
                acc[d*2+0] = fmaf(xv.z, W[lb+2].x, acc[d*2+0]); \
                acc[d*2+0] = fmaf(xv.w, W[lb+3].x, acc[d*2+0]); \
                acc[d*2+1] = fmaf(xv.x, W[lb+0].y, acc[d*2+1]); \
                acc[d*2+1] = fmaf(xv.y, W[lb+1].y, acc[d*2+1]); \
                acc[d*2+1] = fmaf(xv.z, W[lb+2].y, acc[d*2+1]); \
                acc[d*2+1] = fmaf(xv.w, W[lb+3].y, acc[d*2+1]); \
            } }

        LOADW_B(wA, 0);
        for (int m0 = 0; m0 < MULT; m0 += 8) {
            LOADW_B(wB, m0 + 4);                      // prefetch next chunk
            FMA_B(wA, m0);
            if (m0 < MULT - 8) LOADW_B(wA, m0 + 8);   // prefetch chunk after
            FMA_B(wB, m0 + 4);
        }
        #undef LOADW_B
        #undef FMA_B

        #pragma unroll
        for (int d = 0; d < 9; ++d) {
            float2 v = make_float2(acc[d*2+0] * s128, acc[d*2+1] * s128);
            *(float2*)(sXc + ((side * 9 + d) * 2 + n) * 128 + c2) = v;
        }
    }
    __syncthreads();

    // Stage C: SPARSE z = G : (xc o yc). thread=(c, dz-half), both nodes;
    // 162 rule-allowed terms (R4-proven bit-exact).
    {
        const int c = tid & 127;
        const int half = __builtin_amdgcn_readfirstlane(tid >> 7);
        float xr0[9], xr1[9], yr0[9], yr1[9];
        #pragma unroll
        for (int d = 0; d < 9; ++d) {
            xr0[d] = sXc[(d * 2 + 0) * 128 + c];
            xr1[d] = sXc[(d * 2 + 1) * 128 + c];
            yr0[d] = sXc[((9 + d) * 2 + 0) * 128 + c];
            yr1[d] = sXc[((9 + d) * 2 + 1) * 128 + c];
        }
        if (half == 0) {
            float a0[12], a1[12];
            #pragma unroll
            for (int i = 0; i < 12; ++i) { a0[i] = 0.f; a1[i] = 0.f; }
            c_d1<0, 12, 0>(sG, xr0, xr1, yr0, yr1, a0, a1);
            #pragma unroll
            for (int i = 0; i < 12; ++i) {      // dz 0..11
                sZ[i * 128 + c]        = a0[i];
                sZ[(25 + i) * 128 + c] = a1[i];
            }
        } else {
            float a0[13], a1[13];
            #pragma unroll
            for (int i = 0; i < 13; ++i) { a0[i] = 0.f; a1[i] = 0.f; }
            c_d1<12, 25, 0>(sG, xr0, xr1, yr0, yr1, a0, a1);
            #pragma unroll
            for (int i = 0; i < 13; ++i) {      // dz 12..24
                sZ[(12 + i) * 128 + c] = a0[i];
                sZ[(37 + i) * 128 + c] = a1[i];
            }
        }
    }
    __syncthreads();

    // Stage D: linear_out, wave -> l-aligned d-range, e-pair lanes, direct
    // global stores, no final barrier (waves retire independently).
    float* po = outg + 2 * b * (CH * DZ);
    if      (wave == 0) d_tile<0,  4, 0, 2>(sZ, wzg, po, lane);   // l0+l1
    else if (wave == 1) d_tile<4,  5, 2, 1>(sZ, wzg, po, lane);   // l2
    else if (wave == 2) d_tile<9,  7, 3, 1>(sZ, wzg, po, lane);   // l3
    else                d_tile<16, 9, 4, 1>(sZ, wzg, po, lane);   // l4
}

extern "C" void kernel_launch(void* const* d_in, const int* in_sizes, int n_in,
                              void* d_out, int out_size, void* d_ws, size_t ws_size,
                              hipStream_t stream) {
    static float h_gGt[81 * 28];   // zero-init pads
    static bool built = false;
    if (!built) { host_build_gaunt(h_gGt); built = true; }
    hipMemcpyAsync(d_ws, h_gGt, sizeof(h_gGt), hipMemcpyHostToDevice, stream);

    int N = in_sizes[0] / (MULT * DIN);

    hipLaunchKernelGGL(gaunt_fused, dim3(N / 2), dim3(256), 0, stream,
                       (const float*)d_in[0], (const float*)d_in[1],
                       (const float*)d_in[2], (const float*)d_in[3],
                       (const float*)d_in[4], (float*)d_out, (const float*)d_ws);
}